// Round 17
// baseline (201.660 us; speedup 1.0000x reference)
//
#include <hip/hip_runtime.h>
#include <math.h>

// DTW 2048x2048, squared-diff cost, out = sqrt(DTW[2047][2047]).
//
// TWO-CU pipeline (R16 structure + LDS-u: conveyor-free engine): 2 blocks
// x 4 waves (1 wave/SIMD on two CUs), 8 strips of 256 rows; strip g =
// 4*blockIdx+w; lane l owns strip rows 4l..4l+3. C=2 cols/step (jA =
// tau0+2s-2l, jB = jA+1), CSTEP=64, DSKEW=192, EXTRA=192.
//
// WHY LDS-u (round-17 change): the session law is time ~ ops/step x
// ~5.6cy x steps + ramp (R0..R16, dependency-structure-independent);
// R16's -4 ops = -11us confirmed it. Remaining fat: the u-conveyor
// (2 DPP pairs = 4 VALU/step) transports lane l-1's n3A/n3B to lane l --
// but those values are ALREADY in LDS: lane l-1 wrote cols (jA,jB) to
// the ring at step s-1 (wp[s-1]), which is exactly lane l's read base
// wp + 2s. So: ONE ds_read_b64 per step replaces the conveyor; lane 0's
// base diverges to ringR+tau0 (parent boundary; ring row 0 = INFV
// virtual row -1) or cscr (consumer). DS ops from one wave execute in
// LDS in program order (no waitcnt hazard; compiler preserves order via
// obvious aliasing of wp/rbase). This also kills the rv broadcast
// (it only ever fed lane 0's DPP injection -- pure overhead for 63/64
// lanes). Net -3.5 slots/step: 26 -> 22.5 -> model ~126cy/step, ~97us.
// Risk: read-use distance ~8 slots vs LDS latency -> possible lgkm
// stall; null/regression -> revert to R16 (112.5us).
//
// Read correctness: lane l reads cols (tau0+2s-2l, +1); last writer
// before this read is lane l-1 at step s-1 (lane l itself writes the
// same addr at the END of step s; lane l+1 writes it at step s+1) --
// exactly the needed boundary values. Round start (s=0): lane l-1 wrote
// those cols at step 31 of the previous round. Ramp-in: cols < 0 hit
// the INFV pad (PAD=128 >= lane lag 126). uBp (diag) = u2.y of the
// previous step, register-carried; seed DTW[-1][-1]=0 via b0/tid0 uBp.
//
// Protocol (R14/R16 verbatim -- relaxed agent atomics, barrier drains):
//   producer (b0,w3): pre-engine tau0>=128: lane0 flag = tau0-127
//     (covers copies of round tau0-64, drained by that round's barrier);
//     post-engine: 64 relaxed-atomic stores grow[tau0-126+lane];
//     tau0==TAUMAX+64 (pre-check): flag = FLAGBIG (barrier-drained).
//   consumer (b1,w0): needs cols <= min(tau0+63,2047); cached-flag skip,
//     relaxed spin + sched_barrier, relaxed gloads one round early,
//     parked in cscr at round end; lane 0 reads cscr during the round.
//   Junk safety: cols >= 2048 junk flows rightward only; NaN/negative
//   junk sorts LARGE under unsigned-bitcast min3. No deadlock. Flag
//   memset per launch.
//
// Skews: strip g at g*192, +EXTRA=192 for b1 (gap 384, headroom 130).
// Intra-block LDS ring proof unchanged (producer completed tau0+128,
// lane63 wrote <= tau0+65 >= tau0+63). GTOT = 3712.
//
// Per step (~22 slots): 1 ds_read_b64 (u) + 4 v_pk_add_f32 + 8 min3
// (unsigned-bitcast -> v_min3_u32) + 8 fma + 1 ds_write_b64.
// Guard-free INFV=1e30 scheme as R7 (pads absorb OOB; junk sorts large).
//
// Output: b1/w3 (strip 7), lane 63, row 3 = global 2047, col jB = 2047
// at tau0 = 2112 (TAUMAX), s = 30.

#define NLEN   2048
#define NWL    4
#define CSTEP  64
#define SPB    (CSTEP / 2)
#define DSKEW  192
#define EXTRA  192
#define PAD    128
#define RROW   (PAD + 2176)            // ring cols -128..2175 -> 2304 floats
#define YPAD   128
#define TAUMAX 2112
#define GTOT   (TAUMAX + 7 * DSKEW + EXTRA + CSTEP)   // 3712
#define FLAGBIG (1 << 20)
#define INFV   1e30f

typedef float f32x2 __attribute__((ext_vector_type(2)));

__device__ __forceinline__ float dpp_shr1(float v, float inj) {
    int r = __builtin_amdgcn_update_dpp(
        __builtin_bit_cast(int, inj), __builtin_bit_cast(int, v),
        0x138 /*wave_shr:1*/, 0xF, 0xF, false /*lane0 keeps old=inj*/);
    return __builtin_bit_cast(float, r);
}
__device__ __forceinline__ float rdlane(float v, int l) {
    return __builtin_bit_cast(float,
        __builtin_amdgcn_readlane(__builtin_bit_cast(int, v), l));
}
// 3-input min on non-negative floats via unsigned bit-pattern compare;
// umin+umin fuses to a single v_min3_u32. NaN/inf/negative sort LARGE.
__device__ __forceinline__ float min3f(float a, float b, float c) {
    unsigned ia = __builtin_bit_cast(unsigned, a);
    unsigned ib = __builtin_bit_cast(unsigned, b);
    unsigned ic = __builtin_bit_cast(unsigned, c);
    unsigned m  = __builtin_elementwise_min(
                      __builtin_elementwise_min(ia, ib), ic);
    return __builtin_bit_cast(float, m);
}
// RELAXED spin (no buffer_inv); sched_barrier pins compiler ordering so
// data loads can't be hoisted above the observed flag value.
__device__ __forceinline__ int spinflag(int* flag, int target) {
    int f;
    while ((f = __hip_atomic_load(flag, __ATOMIC_RELAXED,
                                  __HIP_MEMORY_SCOPE_AGENT)) < target)
        __builtin_amdgcn_s_sleep(2);
    __builtin_amdgcn_sched_barrier(0);
    return f;
}
// Relaxed agent-scope atomic load/store: coherent point, bypass L2.
__device__ __forceinline__ float gload(const float* p) {
    unsigned u = __hip_atomic_load((const unsigned*)p, __ATOMIC_RELAXED,
                                   __HIP_MEMORY_SCOPE_AGENT);
    return __builtin_bit_cast(float, u);
}
__device__ __forceinline__ void gstore(float* p, float v) {
    __hip_atomic_store((unsigned*)p, __builtin_bit_cast(unsigned, v),
                       __ATOMIC_RELAXED, __HIP_MEMORY_SCOPE_AGENT);
}
__device__ __forceinline__ void fstore(int* p, int v) {
    __hip_atomic_store(p, v, __ATOMIC_RELAXED, __HIP_MEMORY_SCOPE_AGENT);
}

// ---------------- 2-block (2-CU) kernel ----------------
__global__ __launch_bounds__(256, 1) void dtw_kernel(const float* __restrict__ X,
                                                     const float* __restrict__ Y,
                                                     float* __restrict__ out,
                                                     float* __restrict__ ws) {
    int*   flag = (int*)ws;
    float* grow = ws + 16 + PAD;       // global ring base (col 0)

    __shared__ __align__(16) float yB[YPAD + NLEN + YPAD];
    __shared__ float ring[(NWL + 1) * RROW];
    __shared__ __align__(16) float cscr[CSTEP];   // consumer ring scratch
    float* yS = yB + YPAD;

    const int tid  = threadIdx.x;
    const int w    = tid >> 6;
    const int lane = tid & 63;
    const int b    = blockIdx.x;
    const int skew = (4 * b + w) * DSKEW + (b ? EXTRA : 0);
    const bool isprod = (b == 0) & (w == 3);
    const bool iscons = (b == 1) & (w == 0);

    {   // Y into LDS middle, INFV pads on both sides
        const float4* Y4 = (const float4*)Y;
        float4* y4 = (float4*)(yB + YPAD);
        y4[tid]       = Y4[tid];
        y4[tid + 256] = Y4[tid + 256];
        if (tid < YPAD) {
            yB[tid]               = INFV;
            yB[YPAD + NLEN + tid] = INFV;
        }
    }
    for (int k = tid; k < (NWL + 1) * RROW; k += 256) ring[k] = INFV;
    __syncthreads();

    f32x2 xx0, xx1, xx2, xx3;
    {   // strip rows: 256*(4b+w) + 4*lane
        const float4 xa = *(const float4*)&X[b * 1024 + w * 256 + lane * 4];
        xx0 = (f32x2){xa.x, xa.x}; xx1 = (f32x2){xa.y, xa.y};
        xx2 = (f32x2){xa.z, xa.z}; xx3 = (f32x2){xa.w, xa.w};
    }

    float pB0 = INFV, pB1 = INFV, pB2 = INFV, pB3 = INFV;
    float uBp = (b == 0 && tid == 0) ? 0.0f : INFV;  // DTW[-1][-1]=0 seed
    float gnext = INFV;                              // consumer prefetch reg
    int   fc   = 0;                                  // cached flag value

    const float* ringR = ring + w * RROW + PAD;
    float*       ringW = ring + (w + 1) * RROW + PAD;

    for (int gb = 0; gb < GTOT; gb += CSTEP) {
        const int tau0 = gb - skew;

        // producer tail publish: round TAUMAX's stores are barrier-drained
        if (isprod && tau0 == TAUMAX + CSTEP && lane == 0)
            fstore(flag, FLAGBIG);

        if (tau0 >= 0 && tau0 <= TAUMAX) {
            // producer: deferred flag, covers stores of round tau0-64
            // (drained by the intervening __syncthreads vmcnt(0))
            if (isprod && tau0 >= 128 && lane == 0)
                fstore(flag, tau0 - 127);

            bool docp = false;                         // consumer cscr update?
            if (iscons) {
                if (tau0 == 0) {                       // prologue: first block
                    fc = spinflag(flag, 63);
                    cscr[lane] = gload(grow + lane);   // same-wave lgkm order
                }
                const int nt = tau0 + CSTEP;           // prefetch next block
                if (nt <= TAUMAX) {
                    int tgt = nt + 63;
                    if (tgt > NLEN - 1) tgt = NLEN - 1;
                    if (fc < tgt) fc = spinflag(flag, tgt);  // usually skipped
                    gnext = gload(grow + nt + lane);   // latency hidden
                    docp = true;
                }
            }

            f32x2 y2[SPB];
            {
                const f32x2* yp = (const f32x2*)(yS + (tau0 - 2 * lane));
                #pragma unroll
                for (int k = 0; k < SPB; ++k) y2[k] = yp[k];
            }
            float* wp = ringW + (tau0 - 2 * lane);
            // u-read base: lane l>=1 reads its own write base (last writer
            // of those cols = lane l-1 at step s-1, in-order DS semantics);
            // lane 0 reads the parent boundary (ringR) or cscr (consumer).
            const float* rbase = (lane == 0)
                               ? (iscons ? cscr : (ringR + tau0))
                               : (const float*)wp;
            const bool isout = (b == 1) & (w == 3) & (lane == 63)
                             & (tau0 == TAUMAX);

            #pragma unroll
            for (int s = 0; s < SPB; ++s) {
                // boundary (row-above) values for cols (jA, jB): one
                // ds_read_b64; contiguous-descending across lanes.
                const f32x2 u2 = *(const f32x2*)(rbase + 2 * s);
                const float uA = u2.x;
                const float uB = u2.y;
                const f32x2 yv = y2[s];
                f32x2 d0 = xx0 - yv;
                float n0A = fmaf(d0.x, d0.x, min3f(pB0, uA,  uBp));
                float n0B = fmaf(d0.y, d0.y, min3f(n0A, uB,  uA));
                f32x2 d1 = xx1 - yv;
                float n1A = fmaf(d1.x, d1.x, min3f(pB1, n0A, pB0));
                float n1B = fmaf(d1.y, d1.y, min3f(n1A, n0B, n0A));
                f32x2 d2 = xx2 - yv;
                float n2A = fmaf(d2.x, d2.x, min3f(pB2, n1A, pB1));
                float n2B = fmaf(d2.y, d2.y, min3f(n2A, n1B, n1A));
                f32x2 d3 = xx3 - yv;
                float n3A = fmaf(d3.x, d3.x, min3f(pB3, n2A, pB2));
                float n3B = fmaf(d3.y, d3.y, min3f(n3A, n2B, n2A));
                f32x2 wv; wv.x = n3A; wv.y = n3B;
                *(f32x2*)(wp + 2 * s) = wv;            // ds_write_b64
                uBp = uB;
                pB0 = n0B; pB1 = n1B; pB2 = n2B; pB3 = n3B;
                if (s == 30 && isout) out[0] = sqrtf(n3B);  // col 2047
            }

            if (isprod) {
                // newly-final cols -> coherent point (write-through
                // relaxed agent atomics; 256B; drained at the barrier)
                gstore(grow + (tau0 - 126 + lane), ringW[tau0 - 126 + lane]);
            }
            if (docp) cscr[lane] = gnext;              // park for next round
        }
        __syncthreads();
    }
}

// ---------------- fallback: R7 single-block kernel (proven 134.5us) ----------------
#define FNW    4
#define FGTOT  (TAUMAX + (FNW - 1) * DSKEW + CSTEP)   // 2752

__global__ __launch_bounds__(256, 1) void dtw_kernel_fb(const float* __restrict__ X,
                                                        const float* __restrict__ Y,
                                                        float* __restrict__ out) {
    __shared__ __align__(16) float yB[YPAD + NLEN + YPAD];
    __shared__ float ring[(FNW + 1) * RROW];
    float* yS = yB + YPAD;

    const int tid  = threadIdx.x;
    const int w    = tid >> 6;
    const int lane = tid & 63;

    {
        const float4* Y4 = (const float4*)Y;
        float4* y4 = (float4*)(yB + YPAD);
        y4[tid]       = Y4[tid];
        y4[tid + 256] = Y4[tid + 256];
        if (tid < YPAD) {
            yB[tid]               = INFV;
            yB[YPAD + NLEN + tid] = INFV;
        }
    }
    for (int k = tid; k < (FNW + 1) * RROW; k += 256) ring[k] = INFV;
    __syncthreads();

    f32x2 xx0, xx1, xx2, xx3, xx4, xx5, xx6, xx7;
    {
        const float4 xa = *(const float4*)&X[tid * 8];
        const float4 xb = *(const float4*)&X[tid * 8 + 4];
        xx0 = (f32x2){xa.x, xa.x}; xx1 = (f32x2){xa.y, xa.y};
        xx2 = (f32x2){xa.z, xa.z}; xx3 = (f32x2){xa.w, xa.w};
        xx4 = (f32x2){xb.x, xb.x}; xx5 = (f32x2){xb.y, xb.y};
        xx6 = (f32x2){xb.z, xb.z}; xx7 = (f32x2){xb.w, xb.w};
    }

    float pB0 = INFV, pB1 = INFV, pB2 = INFV, pB3 = INFV;
    float pB4 = INFV, pB5 = INFV, pB6 = INFV, pB7 = INFV;
    float a7p = INFV;
    float uBp = (tid == 0) ? 0.0f : INFV;

    const float* ringR = ring + w * RROW + PAD;
    float*       ringW = ring + (w + 1) * RROW + PAD;

    for (int gb = 0; gb < FGTOT; gb += CSTEP) {
        const int tau0 = gb - w * DSKEW;

        if (tau0 >= 0 && tau0 <= TAUMAX) {
            const float rblk = ringR[tau0 + lane];
            f32x2 y2[SPB];
            {
                const f32x2* yp = (const f32x2*)(yS + (tau0 - 2 * lane));
                #pragma unroll
                for (int k = 0; k < SPB; ++k) y2[k] = yp[k];
            }
            float* wp = ringW + (tau0 - 2 * lane);
            const bool isout = (tau0 == TAUMAX) & (w == FNW - 1) & (lane == 63);

            #pragma unroll
            for (int s = 0; s < SPB; ++s) {
                const float riA = rdlane(rblk, 2 * s);
                const float riB = rdlane(rblk, 2 * s + 1);
                const float uA  = dpp_shr1(a7p, riA);
                const float uB  = dpp_shr1(pB7, riB);
                const f32x2 yv = y2[s];
                f32x2 d0 = xx0 - yv;
                float n0A = fmaf(d0.x, d0.x, min3f(pB0, uA,  uBp));
                float n0B = fmaf(d0.y, d0.y, min3f(n0A, uB,  uA));
                f32x2 d1 = xx1 - yv;
                float n1A = fmaf(d1.x, d1.x, min3f(pB1, n0A, pB0));
                float n1B = fmaf(d1.y, d1.y, min3f(n1A, n0B, n0A));
                f32x2 d2 = xx2 - yv;
                float n2A = fmaf(d2.x, d2.x, min3f(pB2, n1A, pB1));
                float n2B = fmaf(d2.y, d2.y, min3f(n2A, n1B, n1A));
                f32x2 d3 = xx3 - yv;
                float n3A = fmaf(d3.x, d3.x, min3f(pB3, n2A, pB2));
                float n3B = fmaf(d3.y, d3.y, min3f(n3A, n2B, n2A));
                f32x2 d4 = xx4 - yv;
                float n4A = fmaf(d4.x, d4.x, min3f(pB4, n3A, pB3));
                float n4B = fmaf(d4.y, d4.y, min3f(n4A, n3B, n3A));
                f32x2 d5 = xx5 - yv;
                float n5A = fmaf(d5.x, d5.x, min3f(pB5, n4A, pB4));
                float n5B = fmaf(d5.y, d5.y, min3f(n5A, n4B, n4A));
                f32x2 d6 = xx6 - yv;
                float n6A = fmaf(d6.x, d6.x, min3f(pB6, n5A, pB5));
                float n6B = fmaf(d6.y, d6.y, min3f(n6A, n5B, n5A));
                f32x2 d7 = xx7 - yv;
                float n7A = fmaf(d7.x, d7.x, min3f(pB7, n6A, pB6));
                float n7B = fmaf(d7.y, d7.y, min3f(n7A, n6B, n6A));
                f32x2 wv; wv.x = n7A; wv.y = n7B;
                *(f32x2*)(wp + 2 * s) = wv;
                uBp = uB; a7p = n7A;
                pB0 = n0B; pB1 = n1B; pB2 = n2B; pB3 = n3B;
                pB4 = n4B; pB5 = n5B; pB6 = n6B; pB7 = n7B;
                if (s == 30 && isout) out[0] = sqrtf(n7B);
            }
        }
        __syncthreads();
    }
}

extern "C" void kernel_launch(void* const* d_in, const int* in_sizes, int n_in,
                              void* d_out, int out_size, void* d_ws, size_t ws_size,
                              hipStream_t stream) {
    const float* x = (const float*)d_in[0];
    const float* y = (const float*)d_in[1];
    (void)in_sizes; (void)n_in; (void)out_size;
    if (d_ws != nullptr && ws_size >= 16384) {
        hipMemsetAsync(d_ws, 0, 4, stream);          // zero the flag
        dtw_kernel<<<2, 256, 0, stream>>>(x, y, (float*)d_out, (float*)d_ws);
    } else {
        dtw_kernel_fb<<<1, 256, 0, stream>>>(x, y, (float*)d_out);
    }
}

// Round 18
// 167.107 us; speedup vs baseline: 1.2068x; 1.2068x over previous
//
#include <hip/hip_runtime.h>
#include <math.h>

// DTW 2048x2048, squared-diff cost, out = sqrt(DTW[2047][2047]).
//
// TWO-CU pipeline (R16 champion, re-banked): 2 blocks x 4 waves (1 wave/
// SIMD on two CUs), 8 strips of 256 rows; strip g = 4*blockIdx+w; lane l
// owns strip rows 4l..4l+3. C=2 cols/step (jA = tau0+2s-2l, jB = jA+1),
// CSTEP=64, DSKEW=192, EXTRA=192.
//
// SESSION LAW (R0-R17): wall-time ~ slots/step x ~5.5cy x steps + ramp,
// independent of dependency structure (1 wave/SIMD issue cadence).
// Ladder: R0 149.6 (C=1,R=8) -> R7 134.5 (C=2) -> R10 127 (2-CU) ->
// R14 123.8 (fenceless) -> R16 112.5 (broadcast rv kills readlane+movs).
// R17 (conveyor via per-step LDS read) REGRESSED to 156.6: per-step LDS
// write->read turnaround (~58cy lgkm stall) -- conveyor data must stay
// in registers. Config sweep on the calibrated model: 4-CU R=2 = null
// (fixed per-wave overhead doesn't shrink), C=4 = worse (conveyor+ramp
// scale with C), CSTEP 32/128 = worse, 2 waves/SIMD = convoy (3.8cy/op).
// This structure is the design-space optimum; re-banking it.
//
// Protocol (R14 verbatim -- relaxed agent atomics, barrier drains):
//   producer (b0,w3): pre-engine, tau0>=128: lane0 flag = tau0-127
//     (covers copies of round tau0-64, drained by that round's barrier
//     __syncthreads vmcnt(0)); post-engine: 64 relaxed-atomic stores
//     grow[tau0-126+lane]; tau0==TAUMAX+64 (pre-check): flag = FLAGBIG.
//   consumer (b1,w0): needs cols <= min(tau0+63,2047); cached-flag skip
//     (flag is monotone; headroom 130 cols means ~2/3 of checks hit the
//     register), relaxed spin + sched_barrier, relaxed gloads one round
//     early, parked in cscr at round end.
//   Junk safety: cols >= 2048 junk flows rightward only (never into
//   output col 2047); NaN/negative junk sorts LARGE under unsigned-
//   bitcast min3. No deadlock: b0 never waits; all consumer targets
//   eventually published (FLAGBIG). Flag memset per launch.
//
// Skews: strip g at g*192, +EXTRA=192 for b1 (gap 384, headroom 130).
// Intra-block LDS ring proof: producer wave w-1 at the barrier completed
// round tau0+128; its lane63 (lag 126) wrote cols <= tau0+65 >= tau0+63.
// GTOT = 3712.
//
// Per step (~23 slots): 2 dpp pairs (u conveyor; injection from rv
// broadcast = compile-time subregister extract, 0 VALU) + 4 v_pk_add_f32
// + 8 min3 (unsigned-bitcast -> v_min3_u32) + 8 fma + 1 ds_write_b64.
// Per round: 16 uniform ds_read_b128 (rv broadcast, conflict-free) +
// 32 ds_read_b64 (y window). Guard-free INFV=1e30 scheme (INFV pads
// absorb OOB; 1e30 + d^2 == 1e30 in fp32).
//
// Output: b1/w3 (strip 7), lane 63, row 3 = global 2047, col jB = 2047
// at tau0 = 2112 (TAUMAX), s = 30.

#define NLEN   2048
#define NWL    4
#define CSTEP  64
#define SPB    (CSTEP / 2)
#define DSKEW  192
#define EXTRA  192
#define PAD    128
#define RROW   (PAD + 2176)            // ring cols -128..2175 -> 2304 floats
#define YPAD   128
#define TAUMAX 2112
#define GTOT   (TAUMAX + 7 * DSKEW + EXTRA + CSTEP)   // 3712
#define FLAGBIG (1 << 20)
#define INFV   1e30f

typedef float f32x2 __attribute__((ext_vector_type(2)));
typedef float f32x4 __attribute__((ext_vector_type(4)));

__device__ __forceinline__ float dpp_shr1(float v, float inj) {
    int r = __builtin_amdgcn_update_dpp(
        __builtin_bit_cast(int, inj), __builtin_bit_cast(int, v),
        0x138 /*wave_shr:1*/, 0xF, 0xF, false /*lane0 keeps old=inj*/);
    return __builtin_bit_cast(float, r);
}
// 3-input min on non-negative floats via unsigned bit-pattern compare;
// umin+umin fuses to a single v_min3_u32. NaN/inf/negative sort LARGE.
__device__ __forceinline__ float min3f(float a, float b, float c) {
    unsigned ia = __builtin_bit_cast(unsigned, a);
    unsigned ib = __builtin_bit_cast(unsigned, b);
    unsigned ic = __builtin_bit_cast(unsigned, c);
    unsigned m  = __builtin_elementwise_min(
                      __builtin_elementwise_min(ia, ib), ic);
    return __builtin_bit_cast(float, m);
}
// RELAXED spin (no buffer_inv); sched_barrier pins compiler ordering so
// data loads can't be hoisted above the observed flag value.
__device__ __forceinline__ int spinflag(int* flag, int target) {
    int f;
    while ((f = __hip_atomic_load(flag, __ATOMIC_RELAXED,
                                  __HIP_MEMORY_SCOPE_AGENT)) < target)
        __builtin_amdgcn_s_sleep(2);
    __builtin_amdgcn_sched_barrier(0);
    return f;
}
// Relaxed agent-scope atomic load/store: coherent point, bypass L2.
__device__ __forceinline__ float gload(const float* p) {
    unsigned u = __hip_atomic_load((const unsigned*)p, __ATOMIC_RELAXED,
                                   __HIP_MEMORY_SCOPE_AGENT);
    return __builtin_bit_cast(float, u);
}
__device__ __forceinline__ void gstore(float* p, float v) {
    __hip_atomic_store((unsigned*)p, __builtin_bit_cast(unsigned, v),
                       __ATOMIC_RELAXED, __HIP_MEMORY_SCOPE_AGENT);
}
__device__ __forceinline__ void fstore(int* p, int v) {
    __hip_atomic_store(p, v, __ATOMIC_RELAXED, __HIP_MEMORY_SCOPE_AGENT);
}

// ---------------- 2-block (2-CU) kernel ----------------
__global__ __launch_bounds__(256, 1) void dtw_kernel(const float* __restrict__ X,
                                                     const float* __restrict__ Y,
                                                     float* __restrict__ out,
                                                     float* __restrict__ ws) {
    int*   flag = (int*)ws;
    float* grow = ws + 16 + PAD;       // global ring base (col 0)

    __shared__ __align__(16) float yB[YPAD + NLEN + YPAD];
    __shared__ float ring[(NWL + 1) * RROW];
    __shared__ __align__(16) float cscr[CSTEP];   // consumer ring scratch
    float* yS = yB + YPAD;

    const int tid  = threadIdx.x;
    const int w    = tid >> 6;
    const int lane = tid & 63;
    const int b    = blockIdx.x;
    const int skew = (4 * b + w) * DSKEW + (b ? EXTRA : 0);
    const bool isprod = (b == 0) & (w == 3);
    const bool iscons = (b == 1) & (w == 0);

    {   // Y into LDS middle, INFV pads on both sides
        const float4* Y4 = (const float4*)Y;
        float4* y4 = (float4*)(yB + YPAD);
        y4[tid]       = Y4[tid];
        y4[tid + 256] = Y4[tid + 256];
        if (tid < YPAD) {
            yB[tid]               = INFV;
            yB[YPAD + NLEN + tid] = INFV;
        }
    }
    for (int k = tid; k < (NWL + 1) * RROW; k += 256) ring[k] = INFV;
    __syncthreads();

    f32x2 xx0, xx1, xx2, xx3;
    {   // strip rows: 256*(4b+w) + 4*lane
        const float4 xa = *(const float4*)&X[b * 1024 + w * 256 + lane * 4];
        xx0 = (f32x2){xa.x, xa.x}; xx1 = (f32x2){xa.y, xa.y};
        xx2 = (f32x2){xa.z, xa.z}; xx3 = (f32x2){xa.w, xa.w};
    }

    float pB0 = INFV, pB1 = INFV, pB2 = INFV, pB3 = INFV;
    float a3p = INFV;
    float uBp = (b == 0 && tid == 0) ? 0.0f : INFV;  // DTW[-1][-1]=0 seed
    float gnext = INFV;                              // consumer prefetch reg
    int   fc   = 0;                                  // cached flag value

    const float* ringR = ring + w * RROW + PAD;
    float*       ringW = ring + (w + 1) * RROW + PAD;

    for (int gb = 0; gb < GTOT; gb += CSTEP) {
        const int tau0 = gb - skew;

        // producer tail publish: round TAUMAX's stores are barrier-drained
        if (isprod && tau0 == TAUMAX + CSTEP && lane == 0)
            fstore(flag, FLAGBIG);

        if (tau0 >= 0 && tau0 <= TAUMAX) {
            // producer: deferred flag, covers stores of round tau0-64
            // (drained by the intervening __syncthreads vmcnt(0))
            if (isprod && tau0 >= 128 && lane == 0)
                fstore(flag, tau0 - 127);

            bool docp = false;                         // consumer cscr update?
            if (iscons) {
                if (tau0 == 0) {                       // prologue: first block
                    fc = spinflag(flag, 63);
                    cscr[lane] = gload(grow + lane);   // same-wave lgkm order
                }
                const int nt = tau0 + CSTEP;           // prefetch next block
                if (nt <= TAUMAX) {
                    int tgt = nt + 63;
                    if (tgt > NLEN - 1) tgt = NLEN - 1;
                    if (fc < tgt) fc = spinflag(flag, tgt);  // usually skipped
                    gnext = gload(grow + nt + lane);   // latency hidden
                    docp = true;
                }
            }

            // broadcast ring values: 64 cols in 16 uniform ds_read_b128
            // (wave-uniform address = conflict-free broadcast); per-step
            // extraction is a compile-time subregister pick = 0 VALU.
            const float* rsrc = iscons ? cscr : (ringR + tau0);
            f32x4 rv[16];
            #pragma unroll
            for (int q = 0; q < 16; ++q) rv[q] = *(const f32x4*)(rsrc + 4 * q);

            f32x2 y2[SPB];
            {
                const f32x2* yp = (const f32x2*)(yS + (tau0 - 2 * lane));
                #pragma unroll
                for (int k = 0; k < SPB; ++k) y2[k] = yp[k];
            }
            float* wp = ringW + (tau0 - 2 * lane);
            const bool isout = (b == 1) & (w == 3) & (lane == 63)
                             & (tau0 == TAUMAX);

            #pragma unroll
            for (int s = 0; s < SPB; ++s) {
                const float riA = rv[s >> 1][(2 * s) & 3];      // ring[tau0+2s]
                const float riB = rv[s >> 1][(2 * s + 1) & 3];  // ring[tau0+2s+1]
                const float uA  = dpp_shr1(a3p, riA);
                const float uB  = dpp_shr1(pB3, riB);
                const f32x2 yv = y2[s];
                f32x2 d0 = xx0 - yv;
                float n0A = fmaf(d0.x, d0.x, min3f(pB0, uA,  uBp));
                float n0B = fmaf(d0.y, d0.y, min3f(n0A, uB,  uA));
                f32x2 d1 = xx1 - yv;
                float n1A = fmaf(d1.x, d1.x, min3f(pB1, n0A, pB0));
                float n1B = fmaf(d1.y, d1.y, min3f(n1A, n0B, n0A));
                f32x2 d2 = xx2 - yv;
                float n2A = fmaf(d2.x, d2.x, min3f(pB2, n1A, pB1));
                float n2B = fmaf(d2.y, d2.y, min3f(n2A, n1B, n1A));
                f32x2 d3 = xx3 - yv;
                float n3A = fmaf(d3.x, d3.x, min3f(pB3, n2A, pB2));
                float n3B = fmaf(d3.y, d3.y, min3f(n3A, n2B, n2A));
                f32x2 wv; wv.x = n3A; wv.y = n3B;
                *(f32x2*)(wp + 2 * s) = wv;            // ds_write_b64
                uBp = uB; a3p = n3A;
                pB0 = n0B; pB1 = n1B; pB2 = n2B; pB3 = n3B;
                if (s == 30 && isout) out[0] = sqrtf(n3B);  // col 2047
            }

            if (isprod) {
                // newly-final cols -> coherent point (write-through
                // relaxed agent atomics; 256B; drained at the barrier)
                gstore(grow + (tau0 - 126 + lane), ringW[tau0 - 126 + lane]);
            }
            if (docp) cscr[lane] = gnext;              // park for next round
        }
        __syncthreads();
    }
}

// ---------------- fallback: R7 single-block kernel (proven 134.5us) ----------------
#define FNW    4
#define FGTOT  (TAUMAX + (FNW - 1) * DSKEW + CSTEP)   // 2752

__device__ __forceinline__ float rdlane(float v, int l) {
    return __builtin_bit_cast(float,
        __builtin_amdgcn_readlane(__builtin_bit_cast(int, v), l));
}

__global__ __launch_bounds__(256, 1) void dtw_kernel_fb(const float* __restrict__ X,
                                                        const float* __restrict__ Y,
                                                        float* __restrict__ out) {
    __shared__ __align__(16) float yB[YPAD + NLEN + YPAD];
    __shared__ float ring[(FNW + 1) * RROW];
    float* yS = yB + YPAD;

    const int tid  = threadIdx.x;
    const int w    = tid >> 6;
    const int lane = tid & 63;

    {
        const float4* Y4 = (const float4*)Y;
        float4* y4 = (float4*)(yB + YPAD);
        y4[tid]       = Y4[tid];
        y4[tid + 256] = Y4[tid + 256];
        if (tid < YPAD) {
            yB[tid]               = INFV;
            yB[YPAD + NLEN + tid] = INFV;
        }
    }
    for (int k = tid; k < (FNW + 1) * RROW; k += 256) ring[k] = INFV;
    __syncthreads();

    f32x2 xx0, xx1, xx2, xx3, xx4, xx5, xx6, xx7;
    {
        const float4 xa = *(const float4*)&X[tid * 8];
        const float4 xb = *(const float4*)&X[tid * 8 + 4];
        xx0 = (f32x2){xa.x, xa.x}; xx1 = (f32x2){xa.y, xa.y};
        xx2 = (f32x2){xa.z, xa.z}; xx3 = (f32x2){xa.w, xa.w};
        xx4 = (f32x2){xb.x, xb.x}; xx5 = (f32x2){xb.y, xb.y};
        xx6 = (f32x2){xb.z, xb.z}; xx7 = (f32x2){xb.w, xb.w};
    }

    float pB0 = INFV, pB1 = INFV, pB2 = INFV, pB3 = INFV;
    float pB4 = INFV, pB5 = INFV, pB6 = INFV, pB7 = INFV;
    float a7p = INFV;
    float uBp = (tid == 0) ? 0.0f : INFV;

    const float* ringR = ring + w * RROW + PAD;
    float*       ringW = ring + (w + 1) * RROW + PAD;

    for (int gb = 0; gb < FGTOT; gb += CSTEP) {
        const int tau0 = gb - w * DSKEW;

        if (tau0 >= 0 && tau0 <= TAUMAX) {
            const float rblk = ringR[tau0 + lane];
            f32x2 y2[SPB];
            {
                const f32x2* yp = (const f32x2*)(yS + (tau0 - 2 * lane));
                #pragma unroll
                for (int k = 0; k < SPB; ++k) y2[k] = yp[k];
            }
            float* wp = ringW + (tau0 - 2 * lane);
            const bool isout = (tau0 == TAUMAX) & (w == FNW - 1) & (lane == 63);

            #pragma unroll
            for (int s = 0; s < SPB; ++s) {
                const float riA = rdlane(rblk, 2 * s);
                const float riB = rdlane(rblk, 2 * s + 1);
                const float uA  = dpp_shr1(a7p, riA);
                const float uB  = dpp_shr1(pB7, riB);
                const f32x2 yv = y2[s];
                f32x2 d0 = xx0 - yv;
                float n0A = fmaf(d0.x, d0.x, min3f(pB0, uA,  uBp));
                float n0B = fmaf(d0.y, d0.y, min3f(n0A, uB,  uA));
                f32x2 d1 = xx1 - yv;
                float n1A = fmaf(d1.x, d1.x, min3f(pB1, n0A, pB0));
                float n1B = fmaf(d1.y, d1.y, min3f(n1A, n0B, n0A));
                f32x2 d2 = xx2 - yv;
                float n2A = fmaf(d2.x, d2.x, min3f(pB2, n1A, pB1));
                float n2B = fmaf(d2.y, d2.y, min3f(n2A, n1B, n1A));
                f32x2 d3 = xx3 - yv;
                float n3A = fmaf(d3.x, d3.x, min3f(pB3, n2A, pB2));
                float n3B = fmaf(d3.y, d3.y, min3f(n3A, n2B, n2A));
                f32x2 d4 = xx4 - yv;
                float n4A = fmaf(d4.x, d4.x, min3f(pB4, n3A, pB3));
                float n4B = fmaf(d4.y, d4.y, min3f(n4A, n3B, n3A));
                f32x2 d5 = xx5 - yv;
                float n5A = fmaf(d5.x, d5.x, min3f(pB5, n4A, pB4));
                float n5B = fmaf(d5.y, d5.y, min3f(n5A, n4B, n4A));
                f32x2 d6 = xx6 - yv;
                float n6A = fmaf(d6.x, d6.x, min3f(pB6, n5A, pB5));
                float n6B = fmaf(d6.y, d6.y, min3f(n6A, n5B, n5A));
                f32x2 d7 = xx7 - yv;
                float n7A = fmaf(d7.x, d7.x, min3f(pB7, n6A, pB6));
                float n7B = fmaf(d7.y, d7.y, min3f(n7A, n6B, n6A));
                f32x2 wv; wv.x = n7A; wv.y = n7B;
                *(f32x2*)(wp + 2 * s) = wv;
                uBp = uB; a7p = n7A;
                pB0 = n0B; pB1 = n1B; pB2 = n2B; pB3 = n3B;
                pB4 = n4B; pB5 = n5B; pB6 = n6B; pB7 = n7B;
                if (s == 30 && isout) out[0] = sqrtf(n7B);
            }
        }
        __syncthreads();
    }
}

extern "C" void kernel_launch(void* const* d_in, const int* in_sizes, int n_in,
                              void* d_out, int out_size, void* d_ws, size_t ws_size,
                              hipStream_t stream) {
    const float* x = (const float*)d_in[0];
    const float* y = (const float*)d_in[1];
    (void)in_sizes; (void)n_in; (void)out_size;
    if (d_ws != nullptr && ws_size >= 16384) {
        hipMemsetAsync(d_ws, 0, 4, stream);          // zero the flag
        dtw_kernel<<<2, 256, 0, stream>>>(x, y, (float*)d_out, (float*)d_ws);
    } else {
        dtw_kernel_fb<<<1, 256, 0, stream>>>(x, y, (float*)d_out);
    }
}

// Round 19
// 165.604 us; speedup vs baseline: 1.2177x; 1.0091x over previous
//
#include <hip/hip_runtime.h>
#include <math.h>

// DTW 2048x2048, squared-diff cost, out = sqrt(DTW[2047][2047]).
//
// TWO-CU pipeline (R16 champion, EXTRA 192->64): 2 blocks x 4 waves
// (1 wave/SIMD on two CUs), 8 strips of 256 rows; strip g = 4*blockIdx+w;
// lane l owns strip rows 4l..4l+3. C=2 cols/step (jA = tau0+2s-2l,
// jB = jA+1), CSTEP=64, DSKEW=192, EXTRA=64.
//
// SESSION LAW (R0-R18): wall-time ~ slots/step x ~5.5cy x steps + round
// overhead, independent of dependency structure (1 wave/SIMD cadence).
// Ladder: R0 149.6 -> R7 134.5 (C=2) -> R10 127 (2-CU) -> R14 123.8
// (fenceless) -> R16/R18 112.5-113.8 (broadcast rv). Design sweep: all
// W/C/CSTEP/2-wave variants null or worse (R3/R9/R11/R17 measured).
// WHY EXTRA=64 (round-19 change): 43% of steps are ramp; DSKEW=192 is
// provably minimal (ring proof lands exactly on tau0+63), but EXTRA=192
// was over-provision -- R12 A/B'd headroom 2 vs 130 cols = NULL. At
// EXTRA=64 the one-round-old flag covers tau0+129 >= needed tau0+127
// with ~4500cy cross-XCD visibility margin (R10 ran 2x at headroom 2).
// GTOT 3712->3584 = -3.4%. Regression/hang -> revert to R18 (~113us).
//
// Protocol (R14/R16 verbatim -- relaxed agent atomics, barrier drains):
//   producer (b0,w3): pre-engine, tau0>=128: lane0 flag = tau0-127
//     (covers copies of round tau0-64, drained by that round's barrier
//     __syncthreads vmcnt(0)); post-engine: 64 relaxed-atomic stores
//     grow[tau0-126+lane]; tau0==TAUMAX+64 (pre-check): flag = FLAGBIG.
//   consumer (b1,w0): needs cols <= min(tau0+63,2047) now and
//     min(tau0+127,2047) for the next-round prefetch; cached-flag skip,
//     relaxed spin + sched_barrier, relaxed gloads one round early,
//     parked in cscr at round end.
//   Junk safety: cols >= 2048 junk flows rightward only (never into
//   output col 2047); NaN/negative junk sorts LARGE under unsigned-
//   bitcast min3. No deadlock: b0 never waits; all consumer targets
//   eventually published (FLAGBIG). Flag memset per launch.
//
// Skews: strip g at g*192, +EXTRA=64 for b1 -> b1w0 vs b0w3 gap = 320,
// headroom 66 cols (1 round). Intra-block LDS ring proof: producer wave
// w-1 at the barrier completed round tau0+128; its lane63 (lag 126)
// wrote cols <= tau0+65 >= tau0+63. GTOT = 2112+7*192+64+64 = 3584.
//
// Per step (~23 slots): 2 dpp pairs (u conveyor; injection from rv
// broadcast = compile-time subregister extract, 0 VALU) + 4 v_pk_add_f32
// + 8 min3 (unsigned-bitcast -> v_min3_u32) + 8 fma + 1 ds_write_b64.
// Per round: 16 uniform ds_read_b128 (rv broadcast, conflict-free) +
// 32 ds_read_b64 (y window). Guard-free INFV=1e30 scheme (INFV pads
// absorb OOB; 1e30 + d^2 == 1e30 in fp32).
//
// Output: b1/w3 (strip 7), lane 63, row 3 = global 2047, col jB = 2047
// at tau0 = 2112 (TAUMAX), s = 30.

#define NLEN   2048
#define NWL    4
#define CSTEP  64
#define SPB    (CSTEP / 2)
#define DSKEW  192
#define EXTRA  64
#define PAD    128
#define RROW   (PAD + 2176)            // ring cols -128..2175 -> 2304 floats
#define YPAD   128
#define TAUMAX 2112
#define GTOT   (TAUMAX + 7 * DSKEW + EXTRA + CSTEP)   // 3584
#define FLAGBIG (1 << 20)
#define INFV   1e30f

typedef float f32x2 __attribute__((ext_vector_type(2)));
typedef float f32x4 __attribute__((ext_vector_type(4)));

__device__ __forceinline__ float dpp_shr1(float v, float inj) {
    int r = __builtin_amdgcn_update_dpp(
        __builtin_bit_cast(int, inj), __builtin_bit_cast(int, v),
        0x138 /*wave_shr:1*/, 0xF, 0xF, false /*lane0 keeps old=inj*/);
    return __builtin_bit_cast(float, r);
}
// 3-input min on non-negative floats via unsigned bit-pattern compare;
// umin+umin fuses to a single v_min3_u32. NaN/inf/negative sort LARGE.
__device__ __forceinline__ float min3f(float a, float b, float c) {
    unsigned ia = __builtin_bit_cast(unsigned, a);
    unsigned ib = __builtin_bit_cast(unsigned, b);
    unsigned ic = __builtin_bit_cast(unsigned, c);
    unsigned m  = __builtin_elementwise_min(
                      __builtin_elementwise_min(ia, ib), ic);
    return __builtin_bit_cast(float, m);
}
// RELAXED spin (no buffer_inv); sched_barrier pins compiler ordering so
// data loads can't be hoisted above the observed flag value.
__device__ __forceinline__ int spinflag(int* flag, int target) {
    int f;
    while ((f = __hip_atomic_load(flag, __ATOMIC_RELAXED,
                                  __HIP_MEMORY_SCOPE_AGENT)) < target)
        __builtin_amdgcn_s_sleep(2);
    __builtin_amdgcn_sched_barrier(0);
    return f;
}
// Relaxed agent-scope atomic load/store: coherent point, bypass L2.
__device__ __forceinline__ float gload(const float* p) {
    unsigned u = __hip_atomic_load((const unsigned*)p, __ATOMIC_RELAXED,
                                   __HIP_MEMORY_SCOPE_AGENT);
    return __builtin_bit_cast(float, u);
}
__device__ __forceinline__ void gstore(float* p, float v) {
    __hip_atomic_store((unsigned*)p, __builtin_bit_cast(unsigned, v),
                       __ATOMIC_RELAXED, __HIP_MEMORY_SCOPE_AGENT);
}
__device__ __forceinline__ void fstore(int* p, int v) {
    __hip_atomic_store(p, v, __ATOMIC_RELAXED, __HIP_MEMORY_SCOPE_AGENT);
}

// ---------------- 2-block (2-CU) kernel ----------------
__global__ __launch_bounds__(256, 1) void dtw_kernel(const float* __restrict__ X,
                                                     const float* __restrict__ Y,
                                                     float* __restrict__ out,
                                                     float* __restrict__ ws) {
    int*   flag = (int*)ws;
    float* grow = ws + 16 + PAD;       // global ring base (col 0)

    __shared__ __align__(16) float yB[YPAD + NLEN + YPAD];
    __shared__ float ring[(NWL + 1) * RROW];
    __shared__ __align__(16) float cscr[CSTEP];   // consumer ring scratch
    float* yS = yB + YPAD;

    const int tid  = threadIdx.x;
    const int w    = tid >> 6;
    const int lane = tid & 63;
    const int b    = blockIdx.x;
    const int skew = (4 * b + w) * DSKEW + (b ? EXTRA : 0);
    const bool isprod = (b == 0) & (w == 3);
    const bool iscons = (b == 1) & (w == 0);

    {   // Y into LDS middle, INFV pads on both sides
        const float4* Y4 = (const float4*)Y;
        float4* y4 = (float4*)(yB + YPAD);
        y4[tid]       = Y4[tid];
        y4[tid + 256] = Y4[tid + 256];
        if (tid < YPAD) {
            yB[tid]               = INFV;
            yB[YPAD + NLEN + tid] = INFV;
        }
    }
    for (int k = tid; k < (NWL + 1) * RROW; k += 256) ring[k] = INFV;
    __syncthreads();

    f32x2 xx0, xx1, xx2, xx3;
    {   // strip rows: 256*(4b+w) + 4*lane
        const float4 xa = *(const float4*)&X[b * 1024 + w * 256 + lane * 4];
        xx0 = (f32x2){xa.x, xa.x}; xx1 = (f32x2){xa.y, xa.y};
        xx2 = (f32x2){xa.z, xa.z}; xx3 = (f32x2){xa.w, xa.w};
    }

    float pB0 = INFV, pB1 = INFV, pB2 = INFV, pB3 = INFV;
    float a3p = INFV;
    float uBp = (b == 0 && tid == 0) ? 0.0f : INFV;  // DTW[-1][-1]=0 seed
    float gnext = INFV;                              // consumer prefetch reg
    int   fc   = 0;                                  // cached flag value

    const float* ringR = ring + w * RROW + PAD;
    float*       ringW = ring + (w + 1) * RROW + PAD;

    for (int gb = 0; gb < GTOT; gb += CSTEP) {
        const int tau0 = gb - skew;

        // producer tail publish: round TAUMAX's stores are barrier-drained
        if (isprod && tau0 == TAUMAX + CSTEP && lane == 0)
            fstore(flag, FLAGBIG);

        if (tau0 >= 0 && tau0 <= TAUMAX) {
            // producer: deferred flag, covers stores of round tau0-64
            // (drained by the intervening __syncthreads vmcnt(0))
            if (isprod && tau0 >= 128 && lane == 0)
                fstore(flag, tau0 - 127);

            bool docp = false;                         // consumer cscr update?
            if (iscons) {
                if (tau0 == 0) {                       // prologue: first block
                    fc = spinflag(flag, 63);
                    cscr[lane] = gload(grow + lane);   // same-wave lgkm order
                }
                const int nt = tau0 + CSTEP;           // prefetch next block
                if (nt <= TAUMAX) {
                    int tgt = nt + 63;
                    if (tgt > NLEN - 1) tgt = NLEN - 1;
                    if (fc < tgt) fc = spinflag(flag, tgt);
                    gnext = gload(grow + nt + lane);   // latency hidden
                    docp = true;
                }
            }

            // broadcast ring values: 64 cols in 16 uniform ds_read_b128
            // (wave-uniform address = conflict-free broadcast); per-step
            // extraction is a compile-time subregister pick = 0 VALU.
            const float* rsrc = iscons ? cscr : (ringR + tau0);
            f32x4 rv[16];
            #pragma unroll
            for (int q = 0; q < 16; ++q) rv[q] = *(const f32x4*)(rsrc + 4 * q);

            f32x2 y2[SPB];
            {
                const f32x2* yp = (const f32x2*)(yS + (tau0 - 2 * lane));
                #pragma unroll
                for (int k = 0; k < SPB; ++k) y2[k] = yp[k];
            }
            float* wp = ringW + (tau0 - 2 * lane);
            const bool isout = (b == 1) & (w == 3) & (lane == 63)
                             & (tau0 == TAUMAX);

            #pragma unroll
            for (int s = 0; s < SPB; ++s) {
                const float riA = rv[s >> 1][(2 * s) & 3];      // ring[tau0+2s]
                const float riB = rv[s >> 1][(2 * s + 1) & 3];  // ring[tau0+2s+1]
                const float uA  = dpp_shr1(a3p, riA);
                const float uB  = dpp_shr1(pB3, riB);
                const f32x2 yv = y2[s];
                f32x2 d0 = xx0 - yv;
                float n0A = fmaf(d0.x, d0.x, min3f(pB0, uA,  uBp));
                float n0B = fmaf(d0.y, d0.y, min3f(n0A, uB,  uA));
                f32x2 d1 = xx1 - yv;
                float n1A = fmaf(d1.x, d1.x, min3f(pB1, n0A, pB0));
                float n1B = fmaf(d1.y, d1.y, min3f(n1A, n0B, n0A));
                f32x2 d2 = xx2 - yv;
                float n2A = fmaf(d2.x, d2.x, min3f(pB2, n1A, pB1));
                float n2B = fmaf(d2.y, d2.y, min3f(n2A, n1B, n1A));
                f32x2 d3 = xx3 - yv;
                float n3A = fmaf(d3.x, d3.x, min3f(pB3, n2A, pB2));
                float n3B = fmaf(d3.y, d3.y, min3f(n3A, n2B, n2A));
                f32x2 wv; wv.x = n3A; wv.y = n3B;
                *(f32x2*)(wp + 2 * s) = wv;            // ds_write_b64
                uBp = uB; a3p = n3A;
                pB0 = n0B; pB1 = n1B; pB2 = n2B; pB3 = n3B;
                if (s == 30 && isout) out[0] = sqrtf(n3B);  // col 2047
            }

            if (isprod) {
                // newly-final cols -> coherent point (write-through
                // relaxed agent atomics; 256B; drained at the barrier)
                gstore(grow + (tau0 - 126 + lane), ringW[tau0 - 126 + lane]);
            }
            if (docp) cscr[lane] = gnext;              // park for next round
        }
        __syncthreads();
    }
}

// ---------------- fallback: R7 single-block kernel (proven 134.5us) ----------------
#define FNW    4
#define FGTOT  (TAUMAX + (FNW - 1) * DSKEW + CSTEP)   // 2752

__device__ __forceinline__ float rdlane(float v, int l) {
    return __builtin_bit_cast(float,
        __builtin_amdgcn_readlane(__builtin_bit_cast(int, v), l));
}

__global__ __launch_bounds__(256, 1) void dtw_kernel_fb(const float* __restrict__ X,
                                                        const float* __restrict__ Y,
                                                        float* __restrict__ out) {
    __shared__ __align__(16) float yB[YPAD + NLEN + YPAD];
    __shared__ float ring[(FNW + 1) * RROW];
    float* yS = yB + YPAD;

    const int tid  = threadIdx.x;
    const int w    = tid >> 6;
    const int lane = tid & 63;

    {
        const float4* Y4 = (const float4*)Y;
        float4* y4 = (float4*)(yB + YPAD);
        y4[tid]       = Y4[tid];
        y4[tid + 256] = Y4[tid + 256];
        if (tid < YPAD) {
            yB[tid]               = INFV;
            yB[YPAD + NLEN + tid] = INFV;
        }
    }
    for (int k = tid; k < (FNW + 1) * RROW; k += 256) ring[k] = INFV;
    __syncthreads();

    f32x2 xx0, xx1, xx2, xx3, xx4, xx5, xx6, xx7;
    {
        const float4 xa = *(const float4*)&X[tid * 8];
        const float4 xb = *(const float4*)&X[tid * 8 + 4];
        xx0 = (f32x2){xa.x, xa.x}; xx1 = (f32x2){xa.y, xa.y};
        xx2 = (f32x2){xa.z, xa.z}; xx3 = (f32x2){xa.w, xa.w};
        xx4 = (f32x2){xb.x, xb.x}; xx5 = (f32x2){xb.y, xb.y};
        xx6 = (f32x2){xb.z, xb.z}; xx7 = (f32x2){xb.w, xb.w};
    }

    float pB0 = INFV, pB1 = INFV, pB2 = INFV, pB3 = INFV;
    float pB4 = INFV, pB5 = INFV, pB6 = INFV, pB7 = INFV;
    float a7p = INFV;
    float uBp = (tid == 0) ? 0.0f : INFV;

    const float* ringR = ring + w * RROW + PAD;
    float*       ringW = ring + (w + 1) * RROW + PAD;

    for (int gb = 0; gb < FGTOT; gb += CSTEP) {
        const int tau0 = gb - w * DSKEW;

        if (tau0 >= 0 && tau0 <= TAUMAX) {
            const float rblk = ringR[tau0 + lane];
            f32x2 y2[SPB];
            {
                const f32x2* yp = (const f32x2*)(yS + (tau0 - 2 * lane));
                #pragma unroll
                for (int k = 0; k < SPB; ++k) y2[k] = yp[k];
            }
            float* wp = ringW + (tau0 - 2 * lane);
            const bool isout = (tau0 == TAUMAX) & (w == FNW - 1) & (lane == 63);

            #pragma unroll
            for (int s = 0; s < SPB; ++s) {
                const float riA = rdlane(rblk, 2 * s);
                const float riB = rdlane(rblk, 2 * s + 1);
                const float uA  = dpp_shr1(a7p, riA);
                const float uB  = dpp_shr1(pB7, riB);
                const f32x2 yv = y2[s];
                f32x2 d0 = xx0 - yv;
                float n0A = fmaf(d0.x, d0.x, min3f(pB0, uA,  uBp));
                float n0B = fmaf(d0.y, d0.y, min3f(n0A, uB,  uA));
                f32x2 d1 = xx1 - yv;
                float n1A = fmaf(d1.x, d1.x, min3f(pB1, n0A, pB0));
                float n1B = fmaf(d1.y, d1.y, min3f(n1A, n0B, n0A));
                f32x2 d2 = xx2 - yv;
                float n2A = fmaf(d2.x, d2.x, min3f(pB2, n1A, pB1));
                float n2B = fmaf(d2.y, d2.y, min3f(n2A, n1B, n1A));
                f32x2 d3 = xx3 - yv;
                float n3A = fmaf(d3.x, d3.x, min3f(pB3, n2A, pB2));
                float n3B = fmaf(d3.y, d3.y, min3f(n3A, n2B, n2A));
                f32x2 d4 = xx4 - yv;
                float n4A = fmaf(d4.x, d4.x, min3f(pB4, n3A, pB3));
                float n4B = fmaf(d4.y, d4.y, min3f(n4A, n3B, n3A));
                f32x2 d5 = xx5 - yv;
                float n5A = fmaf(d5.x, d5.x, min3f(pB5, n4A, pB4));
                float n5B = fmaf(d5.y, d5.y, min3f(n5A, n4B, n4A));
                f32x2 d6 = xx6 - yv;
                float n6A = fmaf(d6.x, d6.x, min3f(pB6, n5A, pB5));
                float n6B = fmaf(d6.y, d6.y, min3f(n6A, n5B, n5A));
                f32x2 d7 = xx7 - yv;
                float n7A = fmaf(d7.x, d7.x, min3f(pB7, n6A, pB6));
                float n7B = fmaf(d7.y, d7.y, min3f(n7A, n6B, n6A));
                f32x2 wv; wv.x = n7A; wv.y = n7B;
                *(f32x2*)(wp + 2 * s) = wv;
                uBp = uB; a7p = n7A;
                pB0 = n0B; pB1 = n1B; pB2 = n2B; pB3 = n3B;
                pB4 = n4B; pB5 = n5B; pB6 = n6B; pB7 = n7B;
                if (s == 30 && isout) out[0] = sqrtf(n7B);
            }
        }
        __syncthreads();
    }
}

extern "C" void kernel_launch(void* const* d_in, const int* in_sizes, int n_in,
                              void* d_out, int out_size, void* d_ws, size_t ws_size,
                              hipStream_t stream) {
    const float* x = (const float*)d_in[0];
    const float* y = (const float*)d_in[1];
    (void)in_sizes; (void)n_in; (void)out_size;
    if (d_ws != nullptr && ws_size >= 16384) {
        hipMemsetAsync(d_ws, 0, 4, stream);          // zero the flag
        dtw_kernel<<<2, 256, 0, stream>>>(x, y, (float*)d_out, (float*)d_ws);
    } else {
        dtw_kernel_fb<<<1, 256, 0, stream>>>(x, y, (float*)d_out);
    }
}